// Round 1
// baseline (1842.777 us; speedup 1.0000x reference)
//
#include <hip/hip_runtime.h>

#define DD 64
#define GG 64
#define EPSV 1e-5f
#define SLOPE 0.01f

#define AG_WAVES 8
#define AG_NPW 8
#define AG_NODES (AG_WAVES*AG_NPW) // 64 nodes per block
#define NRM_NPW 16

// ----------------- CSR build -----------------
__global__ void deg_kernel(const int* __restrict__ src, const int* __restrict__ dst,
                           int* __restrict__ deg_f, int* __restrict__ deg_b, int E) {
  int i = blockIdx.x*blockDim.x + threadIdx.x;
  int stride = gridDim.x*blockDim.x;
  for (int e=i; e<E; e+=stride) {
    atomicAdd(&deg_f[dst[e]], 1);
    atomicAdd(&deg_b[src[e]], 1);
  }
}

__global__ void block_sum_kernel(const int* __restrict__ v, int* __restrict__ partial, int N) {
  __shared__ int sm[1024];
  int i = blockIdx.x*1024 + threadIdx.x;
  sm[threadIdx.x] = (i<N) ? v[i] : 0;
  __syncthreads();
  for (int s=512; s>0; s>>=1) {
    if (threadIdx.x < s) sm[threadIdx.x] += sm[threadIdx.x+s];
    __syncthreads();
  }
  if (threadIdx.x==0) partial[blockIdx.x] = sm[0];
}

__global__ void scan_partial_kernel(int* __restrict__ partial, int nb) {
  // single block of 128 threads; nb <= 128
  __shared__ int sm[128];
  int t = threadIdx.x;
  int v = (t<nb) ? partial[t] : 0;
  int orig = v;
  sm[t] = v; __syncthreads();
  for (int off=1; off<128; off<<=1) {
    int a = (t>=off) ? sm[t-off] : 0;
    __syncthreads();
    v += a; sm[t] = v;
    __syncthreads();
  }
  if (t<nb) partial[t] = v - orig;   // exclusive block offsets
}

__global__ void block_scan_kernel(const int* __restrict__ deg, const int* __restrict__ partial,
                                  int* __restrict__ rp, int* __restrict__ cur, int N, int E) {
  __shared__ int sm[1024];
  int i = blockIdx.x*1024 + threadIdx.x;
  int v = (i<N) ? deg[i] : 0;
  int orig = v;
  sm[threadIdx.x] = v; __syncthreads();
  for (int off=1; off<1024; off<<=1) {
    int a = (threadIdx.x>=off) ? sm[threadIdx.x-off] : 0;
    __syncthreads();
    v += a; sm[threadIdx.x] = v;
    __syncthreads();
  }
  int excl = v - orig + partial[blockIdx.x];
  if (i<N) { rp[i] = excl; cur[i] = excl; }
  if (blockIdx.x==0 && threadIdx.x==0) rp[N] = E;
}

__global__ void fill_kernel(const int* __restrict__ src, const int* __restrict__ dst,
                            int* __restrict__ cur_f, int* __restrict__ cur_b,
                            int* __restrict__ col_f, int* __restrict__ col_b, int E) {
  int i = blockIdx.x*blockDim.x + threadIdx.x;
  int stride = gridDim.x*blockDim.x;
  for (int e=i; e<E; e+=stride) {
    int s = src[e], d = dst[e];
    int p = atomicAdd(&cur_f[d], 1); col_f[p] = s;
    int q = atomicAdd(&cur_b[s], 1); col_b[q] = d;
  }
}

__global__ void cnt_kernel(const int* __restrict__ batch, int* __restrict__ cnt, int N) {
  __shared__ int hist[GG];
  if (threadIdx.x < GG) hist[threadIdx.x] = 0;
  __syncthreads();
  int i = blockIdx.x*blockDim.x + threadIdx.x;
  int stride = gridDim.x*blockDim.x;
  for (int n=i; n<N; n+=stride) atomicAdd(&hist[batch[n]], 1);
  __syncthreads();
  if (threadIdx.x < GG) atomicAdd(&cnt[threadIdx.x], hist[threadIdx.x]);
}

// ----------------- fused mean-agg (both dirs) + dual GEMM + graph-sum -----------------
__global__ __launch_bounds__(512) void agg_gemm_kernel(
    const float* __restrict__ hin,
    const float* __restrict__ Wl, const float* __restrict__ Wr, const float* __restrict__ bias,
    const int* __restrict__ rp_f, const int* __restrict__ col_f,
    const int* __restrict__ rp_b, const int* __restrict__ col_b,
    const int* __restrict__ batch,
    float* __restrict__ t, float* __restrict__ gsum, int N)
{
  __shared__ float wl_s[DD*DD];
  __shared__ float wr_s[DD*DD];
  __shared__ float srow[AG_NODES][DD];
  __shared__ float hrow[AG_NODES][DD];

  // stage weights (16 KB each) to LDS
  {
    const float4* wl4 = (const float4*)Wl;
    const float4* wr4 = (const float4*)Wr;
    float4* wls4 = (float4*)wl_s;
    float4* wrs4 = (float4*)wr_s;
    for (int i=threadIdx.x; i<DD*DD/4; i+=blockDim.x) { wls4[i] = wl4[i]; wrs4[i] = wr4[i]; }
  }

  int wid = threadIdx.x >> 6;
  int lane = threadIdx.x & 63;
  int nodeBase = blockIdx.x*AG_NODES + wid*AG_NPW;

  for (int nn=0; nn<AG_NPW; ++nn) {
    int node = nodeBase + nn;
    float sval = 0.f, hval = 0.f;
    if (node < N) {
      int s0 = rp_f[node], e0 = rp_f[node+1];
      float accf = 0.f;
      for (int base=s0; base<e0; base+=64) {
        int m = e0-base; if (m>64) m=64;
        int jv = (lane<m) ? col_f[base+lane] : 0;
        float a0=0.f,a1=0.f,a2=0.f,a3=0.f;
        int q=0;
        for (; q+3<m; q+=4) {
          int j0=__shfl(jv,q),  j1=__shfl(jv,q+1);
          int j2=__shfl(jv,q+2),j3=__shfl(jv,q+3);
          a0 += hin[j0*DD+lane]; a1 += hin[j1*DD+lane];
          a2 += hin[j2*DD+lane]; a3 += hin[j3*DD+lane];
        }
        for (; q<m; ++q) { int j=__shfl(jv,q); a0 += hin[j*DD+lane]; }
        accf += (a0+a1)+(a2+a3);
      }
      int s1 = rp_b[node], e1 = rp_b[node+1];
      float accb = 0.f;
      for (int base=s1; base<e1; base+=64) {
        int m = e1-base; if (m>64) m=64;
        int jv = (lane<m) ? col_b[base+lane] : 0;
        float a0=0.f,a1=0.f,a2=0.f,a3=0.f;
        int q=0;
        for (; q+3<m; q+=4) {
          int j0=__shfl(jv,q),  j1=__shfl(jv,q+1);
          int j2=__shfl(jv,q+2),j3=__shfl(jv,q+3);
          a0 += hin[j0*DD+lane]; a1 += hin[j1*DD+lane];
          a2 += hin[j2*DD+lane]; a3 += hin[j3*DD+lane];
        }
        for (; q<m; ++q) { int j=__shfl(jv,q); a0 += hin[j*DD+lane]; }
        accb += (a0+a1)+(a2+a3);
      }
      float df = fmaxf((float)(e0-s0), 1.f);
      float db = fmaxf((float)(e1-s1), 1.f);
      sval = 0.5f*(accf/df + accb/db);   // fold the 0.5 here
      hval = hin[node*DD+lane];
    }
    srow[wid*AG_NPW+nn][lane] = sval;
    hrow[wid*AG_NPW+nn][lane] = hval;
  }
  __syncthreads();

  float bv = bias[lane];
  float tacc[AG_NPW];
  #pragma unroll
  for (int nn=0; nn<AG_NPW; ++nn) tacc[nn]=bv;

  for (int k=0; k<DD; k+=4) {
    float w0 = wl_s[(k+0)*DD+lane], w1 = wl_s[(k+1)*DD+lane];
    float w2 = wl_s[(k+2)*DD+lane], w3 = wl_s[(k+3)*DD+lane];
    float r0 = wr_s[(k+0)*DD+lane], r1 = wr_s[(k+1)*DD+lane];
    float r2 = wr_s[(k+2)*DD+lane], r3 = wr_s[(k+3)*DD+lane];
    #pragma unroll
    for (int nn=0; nn<AG_NPW; ++nn) {
      float4 sv = *(const float4*)&srow[wid*AG_NPW+nn][k];
      float4 hv = *(const float4*)&hrow[wid*AG_NPW+nn][k];
      tacc[nn] += sv.x*w0 + sv.y*w1 + sv.z*w2 + sv.w*w3
                + hv.x*r0 + hv.y*r1 + hv.z*r2 + hv.w*r3;
    }
  }

  // write t + per-graph accumulate (batch is sorted -> few flushes)
  int gcur = -1; float gacc = 0.f;
  for (int nn=0; nn<AG_NPW; ++nn) {
    int node = nodeBase+nn;
    if (node >= N) break;
    t[node*DD+lane] = tacc[nn];
    int g = batch[node];
    if (g != gcur) {
      if (gcur >= 0) atomicAdd(&gsum[gcur*DD+lane], gacc);
      gcur = g; gacc = 0.f;
    }
    gacc += tacc[nn];
  }
  if (gcur >= 0) atomicAdd(&gsum[gcur*DD+lane], gacc);
}

// ----------------- GraphNorm pass 1: subtract scaled mean, accumulate var -----------------
__global__ void norm1_kernel(float* __restrict__ t, const float* __restrict__ gsum,
                             const int* __restrict__ cnt, const int* __restrict__ batch,
                             const float* __restrict__ gms, float* __restrict__ vsum, int N)
{
  int wid = (blockIdx.x*blockDim.x + threadIdx.x) >> 6;
  int lane = threadIdx.x & 63;
  int base = wid*NRM_NPW;
  if (base >= N) return;
  float msv = gms[lane];
  int gcur = -1; float mean = 0.f; float vacc = 0.f;
  int end = base+NRM_NPW; if (end>N) end=N;
  for (int node=base; node<end; ++node) {
    int g = batch[node];
    if (g != gcur) {
      if (gcur>=0) atomicAdd(&vsum[gcur*DD+lane], vacc);
      vacc = 0.f;
      float invc = 1.f / fmaxf((float)cnt[g], 1.f);
      mean = gsum[g*DD+lane]*invc;
      gcur = g;
    }
    float u = t[node*DD+lane] - msv*mean;
    t[node*DD+lane] = u;
    vacc += u*u;
  }
  if (gcur>=0) atomicAdd(&vsum[gcur*DD+lane], vacc);
}

// ----------------- GraphNorm pass 2: normalize + affine + leaky + residual -----------------
__global__ void norm2_kernel(const float* __restrict__ t, const float* __restrict__ vsum,
                             const int* __restrict__ cnt, const int* __restrict__ batch,
                             const float* __restrict__ gw, const float* __restrict__ gb,
                             float* __restrict__ h, int resid, int N)
{
  int wid = (blockIdx.x*blockDim.x + threadIdx.x) >> 6;
  int lane = threadIdx.x & 63;
  int base = wid*NRM_NPW;
  if (base >= N) return;
  float wv = gw[lane], bv = gb[lane];
  int gcur=-1; float rs=0.f;
  int end = base+NRM_NPW; if (end>N) end=N;
  for (int node=base; node<end; ++node) {
    int g = batch[node];
    if (g!=gcur) {
      float invc = 1.f/fmaxf((float)cnt[g],1.f);
      rs = rsqrtf(vsum[g*DD+lane]*invc + EPSV);
      gcur=g;
    }
    float u = t[node*DD+lane];
    float y = wv*u*rs + bv;
    y = (y>=0.f) ? y : SLOPE*y;
    float hv = resid ? (h[node*DD+lane] + y) : y;
    h[node*DD+lane] = hv;
  }
}

// ----------------- global mean pool -----------------
__global__ void pool_kernel(const float* __restrict__ h, const int* __restrict__ batch,
                            float* __restrict__ pout, int N)
{
  int wid = (blockIdx.x*blockDim.x + threadIdx.x) >> 6;
  int lane = threadIdx.x & 63;
  int base = wid*NRM_NPW;
  if (base>=N) return;
  int gcur=-1; float acc=0.f;
  int end=base+NRM_NPW; if (end>N) end=N;
  for (int node=base; node<end; ++node) {
    int g = batch[node];
    if (g!=gcur) { if (gcur>=0) atomicAdd(&pout[gcur*DD+lane],acc); acc=0.f; gcur=g; }
    acc += h[node*DD+lane];
  }
  if (gcur>=0) atomicAdd(&pout[gcur*DD+lane],acc);
}

__global__ void finalize_kernel(const float* __restrict__ pout, const int* __restrict__ cnt,
                                float* __restrict__ out)
{
  int i = blockIdx.x*blockDim.x + threadIdx.x;
  if (i < GG*DD) {
    float invc = 1.f/fmaxf((float)cnt[i>>6],1.f);
    out[i] = pout[i]*invc;
  }
}

extern "C" void kernel_launch(void* const* d_in, const int* in_sizes, int n_in,
                              void* d_out, int out_size, void* d_ws, size_t ws_size,
                              hipStream_t stream)
{
  const float* x    = (const float*)d_in[0];
  const int*  ei    = (const int*)d_in[1];
  const int*  batch = (const int*)d_in[2];
  const float* W_l  = (const float*)d_in[3];
  const float* W_r  = (const float*)d_in[4];
  const float* bias = (const float*)d_in[5];
  const float* gn_w = (const float*)d_in[6];
  const float* gn_b = (const float*)d_in[7];
  const float* gn_ms= (const float*)d_in[8];

  int N = in_sizes[2];
  int E = in_sizes[1]/2;
  int L = in_sizes[5]/DD;
  const int* src = ei;
  const int* dst = ei + E;

  // workspace layout
  char* p = (char*)d_ws;
  float* h    = (float*)p; p += (size_t)N*DD*4;
  float* t    = (float*)p; p += (size_t)N*DD*4;
  int* rp_f   = (int*)p; p += (size_t)(N+1)*4;
  int* rp_b   = (int*)p; p += (size_t)(N+1)*4;
  int* cur_f  = (int*)p; p += (size_t)N*4;
  int* cur_b  = (int*)p; p += (size_t)N*4;
  int* col_f  = (int*)p; p += (size_t)E*4;
  int* col_b  = (int*)p; p += (size_t)E*4;
  int* deg_f  = (int*)p; p += (size_t)N*4;
  int* deg_b  = (int*)p; p += (size_t)N*4;
  int* partial= (int*)p; p += 128*4;
  int* cnt    = (int*)p; p += GG*4;
  float* gsum = (float*)p; p += GG*DD*4;
  float* vsum = (float*)p; p += GG*DD*4;
  float* pout = (float*)p; p += GG*DD*4;

  int nb = (N+1023)/1024;

  hipMemsetAsync(deg_f, 0, (size_t)N*4, stream);
  hipMemsetAsync(deg_b, 0, (size_t)N*4, stream);
  hipMemsetAsync(cnt, 0, GG*4, stream);
  hipMemsetAsync(pout, 0, GG*DD*4, stream);

  int eb = 256;
  int eg = (E+eb-1)/eb; if (eg > 2048) eg = 2048;
  deg_kernel<<<eg, eb, 0, stream>>>(src, dst, deg_f, deg_b, E);

  block_sum_kernel<<<nb,1024,0,stream>>>(deg_f, partial, N);
  scan_partial_kernel<<<1,128,0,stream>>>(partial, nb);
  block_scan_kernel<<<nb,1024,0,stream>>>(deg_f, partial, rp_f, cur_f, N, E);
  block_sum_kernel<<<nb,1024,0,stream>>>(deg_b, partial, N);
  scan_partial_kernel<<<1,128,0,stream>>>(partial, nb);
  block_scan_kernel<<<nb,1024,0,stream>>>(deg_b, partial, rp_b, cur_b, N, E);

  fill_kernel<<<eg, eb, 0, stream>>>(src, dst, cur_f, cur_b, col_f, col_b, E);
  cnt_kernel<<<391, 256, 0, stream>>>(batch, cnt, N);

  int agBlocks = (N + AG_NODES-1)/AG_NODES;
  int nrmWaves = (N + NRM_NPW-1)/NRM_NPW;
  int nrmBlocks = (nrmWaves+3)/4;

  for (int i=0; i<L; ++i) {
    const float* hin = (i==0) ? x : h;
    hipMemsetAsync(gsum, 0, GG*DD*4, stream);
    hipMemsetAsync(vsum, 0, GG*DD*4, stream);
    agg_gemm_kernel<<<agBlocks, 512, 0, stream>>>(hin, W_l+(size_t)i*DD*DD, W_r+(size_t)i*DD*DD,
                                                  bias+(size_t)i*DD,
                                                  rp_f, col_f, rp_b, col_b, batch, t, gsum, N);
    norm1_kernel<<<nrmBlocks, 256, 0, stream>>>(t, gsum, cnt, batch, gn_ms+(size_t)i*DD, vsum, N);
    norm2_kernel<<<nrmBlocks, 256, 0, stream>>>(t, vsum, cnt, batch, gn_w+(size_t)i*DD,
                                                gn_b+(size_t)i*DD, h, (i>=2)?1:0, N);
  }
  pool_kernel<<<nrmBlocks, 256, 0, stream>>>(h, batch, pout, N);
  finalize_kernel<<<16, 256, 0, stream>>>(pout, cnt, (float*)d_out);
}

// Round 4
// 1592.413 us; speedup vs baseline: 1.1572x; 1.1572x over previous
//
#include <hip/hip_runtime.h>

#define DD 64
#define GG 64
#define EPSV 1e-5f
#define SLOPE 0.01f

#define AG_WAVES 8
#define AG_NPW 8
#define AG_NODES (AG_WAVES*AG_NPW) // 64 nodes per block
#define NRM_NPW 16
#define NPART 8                    // XCD count on MI355X

// ----------------- CSR build (XCD-partitioned scatter) -----------------
// blocks with blockIdx%8==p own node range [p*npp, (p+1)*npp): their atomics
// and scattered writes stay in one XCD's L2 -> full lines before writeback.
__global__ void deg_kernel(const int* __restrict__ src, const int* __restrict__ dst,
                           int* __restrict__ deg_f, int* __restrict__ deg_b,
                           int E, int npp) {
  int part = blockIdx.x & (NPART-1);
  int lo = part*npp, hi = lo+npp;
  int tid = (blockIdx.x >> 3)*blockDim.x + threadIdx.x;
  int stride = (gridDim.x >> 3)*blockDim.x;
  for (int e=tid; e<E; e+=stride) {
    int d = dst[e], s = src[e];
    if (d >= lo && d < hi) atomicAdd(&deg_f[d], 1);
    if (s >= lo && s < hi) atomicAdd(&deg_b[s], 1);
  }
}

__global__ void fill_kernel(const int* __restrict__ src, const int* __restrict__ dst,
                            int* __restrict__ cur_f, int* __restrict__ cur_b,
                            int* __restrict__ col_f, int* __restrict__ col_b,
                            int E, int npp) {
  int part = blockIdx.x & (NPART-1);
  int lo = part*npp, hi = lo+npp;
  int tid = (blockIdx.x >> 3)*blockDim.x + threadIdx.x;
  int stride = (gridDim.x >> 3)*blockDim.x;
  for (int e=tid; e<E; e+=stride) {
    int s = src[e], d = dst[e];
    if (d >= lo && d < hi) { int p = atomicAdd(&cur_f[d], 1); col_f[p] = s; }
    if (s >= lo && s < hi) { int q = atomicAdd(&cur_b[s], 1); col_b[q] = d; }
  }
}

// ----------------- fused scan over concatenated [deg_f | deg_b] (2N) -----------------
__global__ void block_sum_kernel(const int* __restrict__ v, int* __restrict__ partial, int M) {
  __shared__ int sm[1024];
  int i = blockIdx.x*1024 + threadIdx.x;
  sm[threadIdx.x] = (i<M) ? v[i] : 0;
  __syncthreads();
  for (int s=512; s>0; s>>=1) {
    if (threadIdx.x < s) sm[threadIdx.x] += sm[threadIdx.x+s];
    __syncthreads();
  }
  if (threadIdx.x==0) partial[blockIdx.x] = sm[0];
}

__global__ void scan_partial_kernel(int* __restrict__ partial, int nb) {
  // single block of 256 threads; nb <= 256
  __shared__ int sm[256];
  int t = threadIdx.x;
  int v = (t<nb) ? partial[t] : 0;
  int orig = v;
  sm[t] = v; __syncthreads();
  for (int off=1; off<256; off<<=1) {
    int a = (t>=off) ? sm[t-off] : 0;
    __syncthreads();
    v += a; sm[t] = v;
    __syncthreads();
  }
  if (t<nb) partial[t] = v - orig;   // exclusive block offsets
}

__global__ void block_scan_kernel(const int* __restrict__ deg, const int* __restrict__ partial,
                                  int* __restrict__ rp_f, int* __restrict__ rp_b,
                                  int* __restrict__ cur_f, int* __restrict__ cur_b,
                                  int N, int E) {
  __shared__ int sm[1024];
  int i = blockIdx.x*1024 + threadIdx.x;
  int v = (i<2*N) ? deg[i] : 0;
  int orig = v;
  sm[threadIdx.x] = v; __syncthreads();
  for (int off=1; off<1024; off<<=1) {
    int a = (threadIdx.x>=off) ? sm[threadIdx.x-off] : 0;
    __syncthreads();
    v += a; sm[threadIdx.x] = v;
    __syncthreads();
  }
  int excl = v - orig + partial[blockIdx.x];
  if (i < N)        { rp_f[i] = excl;     cur_f[i] = excl; }
  else if (i < 2*N) { rp_b[i-N] = excl-E; cur_b[i-N] = excl-E; }  // sum(deg_f)==E
  if (blockIdx.x==0 && threadIdx.x==0) { rp_f[N] = E; rp_b[N] = E; }
}

__global__ void cnt_kernel(const int* __restrict__ batch, int* __restrict__ cnt, int N) {
  __shared__ int hist[GG];
  if (threadIdx.x < GG) hist[threadIdx.x] = 0;
  __syncthreads();
  int i = blockIdx.x*blockDim.x + threadIdx.x;
  int stride = gridDim.x*blockDim.x;
  for (int n=i; n<N; n+=stride) atomicAdd(&hist[batch[n]], 1);
  __syncthreads();
  if (threadIdx.x < GG) atomicAdd(&cnt[threadIdx.x], hist[threadIdx.x]);
}

// ----------------- fused mean-agg (both dirs) + dual GEMM + graph-sum -----------------
__global__ __launch_bounds__(512) void agg_gemm_kernel(
    const float* __restrict__ hin,
    const float* __restrict__ Wl, const float* __restrict__ Wr, const float* __restrict__ bias,
    const int* __restrict__ rp_f, const int* __restrict__ col_f,
    const int* __restrict__ rp_b, const int* __restrict__ col_b,
    const int* __restrict__ batch,
    float* __restrict__ t, float* __restrict__ gsum, int N)
{
  __shared__ float wl_s[DD*DD];
  __shared__ float wr_s[DD*DD];
  __shared__ float srow[AG_NODES][DD];
  __shared__ float hrow[AG_NODES][DD];

  {
    const float4* wl4 = (const float4*)Wl;
    const float4* wr4 = (const float4*)Wr;
    float4* wls4 = (float4*)wl_s;
    float4* wrs4 = (float4*)wr_s;
    for (int i=threadIdx.x; i<DD*DD/4; i+=blockDim.x) { wls4[i] = wl4[i]; wrs4[i] = wr4[i]; }
  }

  int wid = threadIdx.x >> 6;
  int lane = threadIdx.x & 63;
  int nodeBase = blockIdx.x*AG_NODES + wid*AG_NPW;

  for (int nn=0; nn<AG_NPW; ++nn) {
    int node = nodeBase + nn;
    float sval = 0.f, hval = 0.f;
    if (node < N) {
      int s0 = rp_f[node], e0 = rp_f[node+1];
      float accf = 0.f;
      for (int base=s0; base<e0; base+=64) {
        int m = e0-base; if (m>64) m=64;
        int jv = (lane<m) ? col_f[base+lane] : 0;
        float a0=0.f,a1=0.f,a2=0.f,a3=0.f;
        int q=0;
        for (; q+3<m; q+=4) {
          int j0=__shfl(jv,q),  j1=__shfl(jv,q+1);
          int j2=__shfl(jv,q+2),j3=__shfl(jv,q+3);
          a0 += hin[j0*DD+lane]; a1 += hin[j1*DD+lane];
          a2 += hin[j2*DD+lane]; a3 += hin[j3*DD+lane];
        }
        for (; q<m; ++q) { int j=__shfl(jv,q); a0 += hin[j*DD+lane]; }
        accf += (a0+a1)+(a2+a3);
      }
      int s1 = rp_b[node], e1 = rp_b[node+1];
      float accb = 0.f;
      for (int base=s1; base<e1; base+=64) {
        int m = e1-base; if (m>64) m=64;
        int jv = (lane<m) ? col_b[base+lane] : 0;
        float a0=0.f,a1=0.f,a2=0.f,a3=0.f;
        int q=0;
        for (; q+3<m; q+=4) {
          int j0=__shfl(jv,q),  j1=__shfl(jv,q+1);
          int j2=__shfl(jv,q+2),j3=__shfl(jv,q+3);
          a0 += hin[j0*DD+lane]; a1 += hin[j1*DD+lane];
          a2 += hin[j2*DD+lane]; a3 += hin[j3*DD+lane];
        }
        for (; q<m; ++q) { int j=__shfl(jv,q); a0 += hin[j*DD+lane]; }
        accb += (a0+a1)+(a2+a3);
      }
      float df = fmaxf((float)(e0-s0), 1.f);
      float db = fmaxf((float)(e1-s1), 1.f);
      sval = 0.5f*(accf/df + accb/db);
      hval = hin[node*DD+lane];
    }
    srow[wid*AG_NPW+nn][lane] = sval;
    hrow[wid*AG_NPW+nn][lane] = hval;
  }
  __syncthreads();

  float bv = bias[lane];
  float tacc[AG_NPW];
  #pragma unroll
  for (int nn=0; nn<AG_NPW; ++nn) tacc[nn]=bv;

  for (int k=0; k<DD; k+=4) {
    float w0 = wl_s[(k+0)*DD+lane], w1 = wl_s[(k+1)*DD+lane];
    float w2 = wl_s[(k+2)*DD+lane], w3 = wl_s[(k+3)*DD+lane];
    float r0 = wr_s[(k+0)*DD+lane], r1 = wr_s[(k+1)*DD+lane];
    float r2 = wr_s[(k+2)*DD+lane], r3 = wr_s[(k+3)*DD+lane];
    #pragma unroll
    for (int nn=0; nn<AG_NPW; ++nn) {
      float4 sv = *(const float4*)&srow[wid*AG_NPW+nn][k];
      float4 hv = *(const float4*)&hrow[wid*AG_NPW+nn][k];
      tacc[nn] += sv.x*w0 + sv.y*w1 + sv.z*w2 + sv.w*w3
                + hv.x*r0 + hv.y*r1 + hv.z*r2 + hv.w*r3;
    }
  }

  int gcur = -1; float gacc = 0.f;
  for (int nn=0; nn<AG_NPW; ++nn) {
    int node = nodeBase+nn;
    if (node >= N) break;
    t[node*DD+lane] = tacc[nn];
    int g = batch[node];
    if (g != gcur) {
      if (gcur >= 0) atomicAdd(&gsum[gcur*DD+lane], gacc);
      gcur = g; gacc = 0.f;
    }
    gacc += tacc[nn];
  }
  if (gcur >= 0) atomicAdd(&gsum[gcur*DD+lane], gacc);
}

// ----------------- GraphNorm pass 1 -----------------
__global__ void norm1_kernel(float* __restrict__ t, const float* __restrict__ gsum,
                             const int* __restrict__ cnt, const int* __restrict__ batch,
                             const float* __restrict__ gms, float* __restrict__ vsum, int N)
{
  int wid = (blockIdx.x*blockDim.x + threadIdx.x) >> 6;
  int lane = threadIdx.x & 63;
  int base = wid*NRM_NPW;
  if (base >= N) return;
  float msv = gms[lane];
  int gcur = -1; float mean = 0.f; float vacc = 0.f;
  int end = base+NRM_NPW; if (end>N) end=N;
  for (int node=base; node<end; ++node) {
    int g = batch[node];
    if (g != gcur) {
      if (gcur>=0) atomicAdd(&vsum[gcur*DD+lane], vacc);
      vacc = 0.f;
      float invc = 1.f / fmaxf((float)cnt[g], 1.f);
      mean = gsum[g*DD+lane]*invc;
      gcur = g;
    }
    float u = t[node*DD+lane] - msv*mean;
    t[node*DD+lane] = u;
    vacc += u*u;
  }
  if (gcur>=0) atomicAdd(&vsum[gcur*DD+lane], vacc);
}

// ----------------- GraphNorm pass 2 -----------------
__global__ void norm2_kernel(const float* __restrict__ t, const float* __restrict__ vsum,
                             const int* __restrict__ cnt, const int* __restrict__ batch,
                             const float* __restrict__ gw, const float* __restrict__ gb,
                             float* __restrict__ h, int resid, int N)
{
  int wid = (blockIdx.x*blockDim.x + threadIdx.x) >> 6;
  int lane = threadIdx.x & 63;
  int base = wid*NRM_NPW;
  if (base >= N) return;
  float wv = gw[lane], bv = gb[lane];
  int gcur=-1; float rs=0.f;
  int end = base+NRM_NPW; if (end>N) end=N;
  for (int node=base; node<end; ++node) {
    int g = batch[node];
    if (g!=gcur) {
      float invc = 1.f/fmaxf((float)cnt[g],1.f);
      rs = rsqrtf(vsum[g*DD+lane]*invc + EPSV);
      gcur=g;
    }
    float u = t[node*DD+lane];
    float y = wv*u*rs + bv;
    y = (y>=0.f) ? y : SLOPE*y;
    float hv = resid ? (h[node*DD+lane] + y) : y;
    h[node*DD+lane] = hv;
  }
}

// ----------------- global mean pool -----------------
__global__ void pool_kernel(const float* __restrict__ h, const int* __restrict__ batch,
                            float* __restrict__ pout, int N)
{
  int wid = (blockIdx.x*blockDim.x + threadIdx.x) >> 6;
  int lane = threadIdx.x & 63;
  int base = wid*NRM_NPW;
  if (base>=N) return;
  int gcur=-1; float acc=0.f;
  int end=base+NRM_NPW; if (end>N) end=N;
  for (int node=base; node<end; ++node) {
    int g = batch[node];
    if (g!=gcur) { if (gcur>=0) atomicAdd(&pout[gcur*DD+lane],acc); acc=0.f; gcur=g; }
    acc += h[node*DD+lane];
  }
  if (gcur>=0) atomicAdd(&pout[gcur*DD+lane],acc);
}

__global__ void finalize_kernel(const float* __restrict__ pout, const int* __restrict__ cnt,
                                float* __restrict__ out)
{
  int i = blockIdx.x*blockDim.x + threadIdx.x;
  if (i < GG*DD) {
    float invc = 1.f/fmaxf((float)cnt[i>>6],1.f);
    out[i] = pout[i]*invc;
  }
}

extern "C" void kernel_launch(void* const* d_in, const int* in_sizes, int n_in,
                              void* d_out, int out_size, void* d_ws, size_t ws_size,
                              hipStream_t stream)
{
  const float* x    = (const float*)d_in[0];
  const int*  ei    = (const int*)d_in[1];
  const int*  batch = (const int*)d_in[2];
  const float* W_l  = (const float*)d_in[3];
  const float* W_r  = (const float*)d_in[4];
  const float* bias = (const float*)d_in[5];
  const float* gn_w = (const float*)d_in[6];
  const float* gn_b = (const float*)d_in[7];
  const float* gn_ms= (const float*)d_in[8];

  int N = in_sizes[2];
  int E = in_sizes[1]/2;
  int L = in_sizes[5]/DD;
  const int* src = ei;
  const int* dst = ei + E;

  // ---- workspace layout: zero-zone first (single memset) ----
  char* p = (char*)d_ws;
  int*   deg   = (int*)p;   p += (size_t)2*N*4;        // [deg_f | deg_b]
  int*   cnt   = (int*)p;   p += GG*4;
  float* gsum  = (float*)p; p += (size_t)L*GG*DD*4;    // per-layer
  float* vsum  = (float*)p; p += (size_t)L*GG*DD*4;    // per-layer
  float* pout  = (float*)p; p += GG*DD*4;
  size_t zeroBytes = (char*)p - (char*)d_ws;

  float* h     = (float*)p; p += (size_t)N*DD*4;
  float* t     = (float*)p; p += (size_t)N*DD*4;
  int* rp_f    = (int*)p; p += (size_t)(N+1)*4;
  int* rp_b    = (int*)p; p += (size_t)(N+1)*4;
  int* cur_f   = (int*)p; p += (size_t)N*4;
  int* cur_b   = (int*)p; p += (size_t)N*4;
  int* col_f   = (int*)p; p += (size_t)E*4;
  int* col_b   = (int*)p; p += (size_t)E*4;
  int* partial = (int*)p; p += 256*4;

  int* deg_f = deg;
  int* deg_b = deg + N;

  hipMemsetAsync(d_ws, 0, zeroBytes, stream);

  int npp = (N + NPART-1)/NPART;
  int eg = 2048;                       // multiple of NPART
  deg_kernel<<<eg, 256, 0, stream>>>(src, dst, deg_f, deg_b, E, npp);
  cnt_kernel<<<391, 256, 0, stream>>>(batch, cnt, N);

  int nb2 = (2*N + 1023)/1024;         // <= 256
  block_sum_kernel<<<nb2, 1024, 0, stream>>>(deg, partial, 2*N);
  scan_partial_kernel<<<1, 256, 0, stream>>>(partial, nb2);
  block_scan_kernel<<<nb2, 1024, 0, stream>>>(deg, partial, rp_f, rp_b, cur_f, cur_b, N, E);

  fill_kernel<<<eg, 256, 0, stream>>>(src, dst, cur_f, cur_b, col_f, col_b, E, npp);

  int agBlocks = (N + AG_NODES-1)/AG_NODES;
  int nrmWaves = (N + NRM_NPW-1)/NRM_NPW;
  int nrmBlocks = (nrmWaves+3)/4;

  for (int i=0; i<L; ++i) {
    const float* hin = (i==0) ? x : h;
    float* gsum_i = gsum + (size_t)i*GG*DD;
    float* vsum_i = vsum + (size_t)i*GG*DD;
    agg_gemm_kernel<<<agBlocks, 512, 0, stream>>>(hin, W_l+(size_t)i*DD*DD, W_r+(size_t)i*DD*DD,
                                                  bias+(size_t)i*DD,
                                                  rp_f, col_f, rp_b, col_b, batch, t, gsum_i, N);
    norm1_kernel<<<nrmBlocks, 256, 0, stream>>>(t, gsum_i, cnt, batch, gn_ms+(size_t)i*DD, vsum_i, N);
    norm2_kernel<<<nrmBlocks, 256, 0, stream>>>(t, vsum_i, cnt, batch, gn_w+(size_t)i*DD,
                                                gn_b+(size_t)i*DD, h, (i>=2)?1:0, N);
  }
  pool_kernel<<<nrmBlocks, 256, 0, stream>>>(h, batch, pout, N);
  finalize_kernel<<<16, 256, 0, stream>>>(pout, cnt, (float*)d_out);
}